// Round 8
// baseline (239.307 us; speedup 1.0000x reference)
//
#include <hip/hip_runtime.h>

#define BB 8192
#define GG 32
#define DD 64

// ---- DPP cross-lane helpers (VALU pipe, rows of 16 lanes) ----
#define QUAD_XOR1 0xB1   // quad_perm [1,0,3,2]
#define QUAD_XOR2 0x4E   // quad_perm [2,3,0,1]
#define ROW_ROR4  0x124
#define ROW_ROR8  0x128

template<int CTRL>
__device__ __forceinline__ float dpp_mov(float x) {
    return __int_as_float(__builtin_amdgcn_update_dpp(
        __float_as_int(x), __float_as_int(x), CTRL, 0xF, 0xF, false));
}
__device__ __forceinline__ float row16_sum(float x) {
    x += dpp_mov<QUAD_XOR1>(x);
    x += dpp_mov<QUAD_XOR2>(x);
    x += dpp_mov<ROW_ROR4>(x);
    x += dpp_mov<ROW_ROR8>(x);
    return x;
}
__device__ __forceinline__ float row16_max(float x) {
    x = fmaxf(x, dpp_mov<QUAD_XOR1>(x));
    x = fmaxf(x, dpp_mov<QUAD_XOR2>(x));
    x = fmaxf(x, dpp_mov<ROW_ROR4>(x));
    x = fmaxf(x, dpp_mov<ROW_ROR8>(x));
    return x;
}
template<int CTRL>
__device__ __forceinline__ int dpp_mov_i(int x) {
    return __builtin_amdgcn_update_dpp(x, x, CTRL, 0xF, 0xF, false);
}
__device__ __forceinline__ int row16_min_i(int x) {
    x = min(x, dpp_mov_i<QUAD_XOR1>(x));
    x = min(x, dpp_mov_i<QUAD_XOR2>(x));
    x = min(x, dpp_mov_i<ROW_ROR4>(x));
    x = min(x, dpp_mov_i<ROW_ROR8>(x));
    return x;
}
__device__ __forceinline__ float half_sum(float x) { x = row16_sum(x); return x + __shfl_xor(x, 16); }
__device__ __forceinline__ float half_max(float x) { x = row16_max(x); return fmaxf(x, __shfl_xor(x, 16)); }
__device__ __forceinline__ int   half_min_i(int x) { x = row16_min_i(x); return min(x, __shfl_xor(x, 16)); }

__global__ __launch_bounds__(256, 4)   // cap 128 VGPR -> 4 waves/SIMD
void hhgr_kernel(const int* __restrict__ group_inputs,
                 const int* __restrict__ item_inputs,
                 const int* __restrict__ members,
                 const float* __restrict__ user_table,
                 const float* __restrict__ item_table,
                 const float* __restrict__ group_table,
                 const float* __restrict__ group_embedds,
                 const float* __restrict__ att_w1, const float* __restrict__ att_b1,
                 const float* __restrict__ att_w2, const float* __restrict__ att_b2,
                 const float* __restrict__ cls_w, const float* __restrict__ cls_b,
                 const float* __restrict__ pred_w1, const float* __restrict__ pred_b1,
                 const float* __restrict__ pred_w2, const float* __restrict__ pred_b2,
                 float* __restrict__ out)
{
    // LDS only for the (statistically dead) weighted-sum branch
    __shared__ float awt_s[8][32];
    __shared__ int   midx_s[8][32];

    const int tid  = threadIdx.x;
    const int m    = tid & 31;            // member index (= lane within half)
    const int slot = tid >> 5;            // 0..7: row slot within block
    const int wl   = tid & 63;
    const int hw   = wl >> 5;             // half within wave
    const int b    = blockIdx.x * 8 + slot;

    const int midx = members[b * GG + m];         // coalesced
    const int iidx = item_inputs[b];
    const int gidx = group_inputs[b];

    const float* urowp = user_table + (size_t)midx * DD;
    const float4* urow = (const float4*)urowp;

    // ---- issue small hot loads FIRST (vmcnt retires in order) ----
    const float itx = item_table[(size_t)iidx * DD + m];        // k = m
    const float ity = item_table[(size_t)iidx * DD + 32 + m];   // k = 32+m
    const float4* wa = (const float4*)(att_w1 + (64 + m) * 16); // one line/lane
    const float4* wb = (const float4*)(att_w1 + (96 + m) * 16);

    // ---- issue first member-row chunk (long-latency scattered gather) ----
    float4 buf0 = urow[0], buf1 = urow[1], buf2 = urow[2], buf3 = urow[3];

    // ---- item half of layer 1 (distributed k = m, 32+m; reduce over half) ----
    float h[16];
#pragma unroll
    for (int q4 = 0; q4 < 4; ++q4) {
        const float4 a  = wa[q4];
        const float4 bq = wb[q4];
        h[4 * q4 + 0] = fmaf(ity, bq.x, itx * a.x);
        h[4 * q4 + 1] = fmaf(ity, bq.y, itx * a.y);
        h[4 * q4 + 2] = fmaf(ity, bq.z, itx * a.z);
        h[4 * q4 + 3] = fmaf(ity, bq.w, itx * a.w);
    }
#pragma unroll
    for (int i = 0; i < 16; ++i)
        h[i] = half_sum(h[i]) + att_b1[i];

    // ---- member half: 4 chunks of 4xfloat4, prefetch next while computing ----
#pragma unroll
    for (int q = 0; q < 4; ++q) {
        float4 n0, n1, n2, n3;
        if (q < 3) { n0 = urow[4*q+4]; n1 = urow[4*q+5]; n2 = urow[4*q+6]; n3 = urow[4*q+7]; }
#pragma unroll
        for (int kk = 0; kk < 4; ++kk) {
            const float4 v = (kk == 0) ? buf0 : (kk == 1) ? buf1 : (kk == 2) ? buf2 : buf3;
            const float* wr = att_w1 + (16 * q + 4 * kk) * 16;   // uniform -> s_load
#pragma unroll
            for (int oo = 0; oo < 16; ++oo) {
                h[oo] = fmaf(v.x, wr[oo],      h[oo]);
                h[oo] = fmaf(v.y, wr[16 + oo], h[oo]);
                h[oo] = fmaf(v.z, wr[32 + oo], h[oo]);
                h[oo] = fmaf(v.w, wr[48 + oo], h[oo]);
            }
        }
        if (q < 3) { buf0 = n0; buf1 = n1; buf2 = n2; buf3 = n3; }
    }

    // ---- layer 2 + score ----
    float sc = att_b2[0];
#pragma unroll
    for (int oo = 0; oo < 16; ++oo)
        sc = fmaf(fmaxf(h[oo], 0.f), att_w2[oo], sc);

    // ---- softmax over 32 members ----
    const float smax = half_max(sc);
    const float e    = expf(sc - smax);
    const float ssum = half_sum(e);
    const float w    = e / ssum;
    out[(size_t)BB * 193 + (size_t)b * GG + m] = w;            // at_wt

    const float wmax = 1.0f / ssum;                            // = max softmax weight
    const int   idx  = half_min_i((sc == smax) ? m : 1000);    // first-max index

    // ---- routing classifier ----
    const float cs0 = fmaf(wmax, cls_w[0], cls_b[0]);
    const float cs1 = fmaf(wmax, cls_w[1], cls_b[1]) + 0.5f;
    const int pred  = (cs1 > cs0) ? 1 : 0;

    // ---- g_att (leader whp; weighted branch kept correct via LDS) ----
    float gA, gB;
    if (pred) {
        const int lmidx = __shfl(midx, hw * 32 + idx);
        const float* lrow = user_table + (size_t)lmidx * DD;   // L1/L2 hot
        gA = lrow[m];
        gB = lrow[m + 32];
    } else {
        awt_s[slot][m]  = w;
        midx_s[slot][m] = midx;
        __builtin_amdgcn_s_waitcnt(0);   // drain lgkm before half reads LDS back
        float accA = 0.f, accB = 0.f;
        for (int g = 0; g < GG; ++g) {
            const float wg = awt_s[slot][g];
            const float* grow = user_table + (size_t)midx_s[slot][g] * DD;
            accA = fmaf(wg, grow[m], accA);
            accB = fmaf(wg, grow[m + 32], accB);
        }
        gA = accA; gB = accB;
    }

    // ---- group-pure + elementwise + new_embeds outputs ----
    const float gpA = group_table[(size_t)gidx * DD + m]      + group_embedds[(size_t)gidx * DD + m];
    const float gpB = group_table[(size_t)gidx * DD + m + 32] + group_embedds[(size_t)gidx * DD + m + 32];
    const float itA = item_table[(size_t)iidx * DD + m];
    const float itB = item_table[(size_t)iidx * DD + m + 32];
    const float gvA = gA + gpA, gvB = gB + gpB;
    const float elA = gvA * itA, elB = gvB * itB;

    const size_t nb = (size_t)b * 192;
    out[nb + m]        = elA;  out[nb + 32 + m]  = elB;   // elem
    out[nb + 64 + m]   = gvA;  out[nb + 96 + m]  = gvB;   // g
    out[nb + 128 + m]  = itA;  out[nb + 160 + m] = itB;   // item

    // ---- predict MLP: 192 -> 8 (relu) -> 1 (sigmoid), distributed over lanes ----
    float p8[8];
#pragma unroll
    for (int j = 0; j < 8; ++j) p8[j] = 0.f;
    {
        const float vals[6] = { elA, elB, gvA, gvB, itA, itB };
        const int   cols[6] = { m, m + 32, 64 + m, 96 + m, 128 + m, 160 + m };
#pragma unroll
        for (int t = 0; t < 6; ++t) {
            const float4* wr = (const float4*)(pred_w1 + cols[t] * 8);
            const float4 w0 = wr[0], w1v = wr[1];
            p8[0] = fmaf(vals[t], w0.x, p8[0]);
            p8[1] = fmaf(vals[t], w0.y, p8[1]);
            p8[2] = fmaf(vals[t], w0.z, p8[2]);
            p8[3] = fmaf(vals[t], w0.w, p8[3]);
            p8[4] = fmaf(vals[t], w1v.x, p8[4]);
            p8[5] = fmaf(vals[t], w1v.y, p8[5]);
            p8[6] = fmaf(vals[t], w1v.z, p8[6]);
            p8[7] = fmaf(vals[t], w1v.w, p8[7]);
        }
    }
#pragma unroll
    for (int j = 0; j < 8; ++j)
        p8[j] = half_sum(p8[j]) + pred_b1[j];

    float t2 = pred_b2[0];
#pragma unroll
    for (int j = 0; j < 8; ++j)
        t2 = fmaf(fmaxf(p8[j], 0.f), pred_w2[j], t2);
    const float yv = 1.f / (1.f + expf(-t2));

    if (m == 0) {
        out[(size_t)BB * 192 + b] = yv;            // y
        out[(size_t)BB * 225 + b] = (float)pred;   // pred_cls
    }
}

extern "C" void kernel_launch(void* const* d_in, const int* in_sizes, int n_in,
                              void* d_out, int out_size, void* d_ws, size_t ws_size,
                              hipStream_t stream) {
    const int*   group_inputs  = (const int*)d_in[0];
    const int*   item_inputs   = (const int*)d_in[1];
    const int*   members       = (const int*)d_in[2];
    const float* user_table    = (const float*)d_in[3];
    const float* item_table    = (const float*)d_in[4];
    const float* group_table   = (const float*)d_in[5];
    const float* group_embedds = (const float*)d_in[6];
    const float* att_w1  = (const float*)d_in[7];
    const float* att_b1  = (const float*)d_in[8];
    const float* att_w2  = (const float*)d_in[9];
    const float* att_b2  = (const float*)d_in[10];
    const float* cls_w   = (const float*)d_in[11];
    const float* cls_b   = (const float*)d_in[12];
    const float* pred_w1 = (const float*)d_in[13];
    const float* pred_b1 = (const float*)d_in[14];
    const float* pred_w2 = (const float*)d_in[15];
    const float* pred_b2 = (const float*)d_in[16];
    float* out = (float*)d_out;

    // MEASUREMENT ROUND: 5 identical idempotent launches.
    // dur_us - 147.4 (round-6 1x baseline) = 4 * K_warm  -> direct kernel cost.
    for (int rep = 0; rep < 5; ++rep) {
        hipLaunchKernelGGL(hhgr_kernel, dim3(BB / 8), dim3(256), 0, stream,
                           group_inputs, item_inputs, members, user_table, item_table,
                           group_table, group_embedds, att_w1, att_b1, att_w2, att_b2,
                           cls_w, cls_b, pred_w1, pred_b1, pred_w2, pred_b2, out);
    }
}

// Round 11
// 145.046 us; speedup vs baseline: 1.6499x; 1.6499x over previous
//
#include <hip/hip_runtime.h>

#define BB 8192
#define GG 32
#define DD 64

// ---- DPP cross-lane helpers (VALU pipe, rows of 16 lanes) ----
#define QUAD_XOR1 0xB1   // quad_perm [1,0,3,2]
#define QUAD_XOR2 0x4E   // quad_perm [2,3,0,1]
#define ROW_ROR4  0x124
#define ROW_ROR8  0x128

template<int CTRL>
__device__ __forceinline__ float dpp_mov(float x) {
    return __int_as_float(__builtin_amdgcn_update_dpp(
        __float_as_int(x), __float_as_int(x), CTRL, 0xF, 0xF, false));
}
__device__ __forceinline__ float row16_sum(float x) {
    x += dpp_mov<QUAD_XOR1>(x);
    x += dpp_mov<QUAD_XOR2>(x);
    x += dpp_mov<ROW_ROR4>(x);
    x += dpp_mov<ROW_ROR8>(x);
    return x;
}
__device__ __forceinline__ float row16_max(float x) {
    x = fmaxf(x, dpp_mov<QUAD_XOR1>(x));
    x = fmaxf(x, dpp_mov<QUAD_XOR2>(x));
    x = fmaxf(x, dpp_mov<ROW_ROR4>(x));
    x = fmaxf(x, dpp_mov<ROW_ROR8>(x));
    return x;
}
template<int CTRL>
__device__ __forceinline__ int dpp_mov_i(int x) {
    return __builtin_amdgcn_update_dpp(x, x, CTRL, 0xF, 0xF, false);
}
__device__ __forceinline__ int row16_min_i(int x) {
    x = min(x, dpp_mov_i<QUAD_XOR1>(x));
    x = min(x, dpp_mov_i<QUAD_XOR2>(x));
    x = min(x, dpp_mov_i<ROW_ROR4>(x));
    x = min(x, dpp_mov_i<ROW_ROR8>(x));
    return x;
}
__device__ __forceinline__ float half_sum(float x) { x = row16_sum(x); return x + __shfl_xor(x, 16); }
__device__ __forceinline__ float half_max(float x) { x = row16_max(x); return fmaxf(x, __shfl_xor(x, 16)); }
__device__ __forceinline__ int   half_min_i(int x) { x = row16_min_i(x); return min(x, __shfl_xor(x, 16)); }

__global__ __launch_bounds__(64)
void hhgr_kernel(const int* __restrict__ group_inputs,
                 const int* __restrict__ item_inputs,
                 const int* __restrict__ members,
                 const float* __restrict__ user_table,
                 const float* __restrict__ item_table,
                 const float* __restrict__ group_table,
                 const float* __restrict__ group_embedds,
                 const float* __restrict__ att_w1, const float* __restrict__ att_b1,
                 const float* __restrict__ att_w2, const float* __restrict__ att_b2,
                 const float* __restrict__ cls_w, const float* __restrict__ cls_b,
                 const float* __restrict__ pred_w1, const float* __restrict__ pred_b1,
                 const float* __restrict__ pred_w2, const float* __restrict__ pred_b2,
                 float* __restrict__ out)
{
    // 64 member rows x 64 floats, 16 KB. LDS linear; GLOBAL source pre-swizzled
    // chunk' = chunk ^ (row&7) so swizzled b128 reads are conflict-free (rule: both sides).
    __shared__ float tile[64 * 64];

    const int wl = threadIdx.x;           // 0..63
    const int m  = wl & 31;               // member index within row
    const int hw = wl >> 5;               // which of the 2 batch rows this wave handles
    const int b  = blockIdx.x * 2 + hw;

    const int midx = members[b * GG + m];       // coalesced
    const int iidx = item_inputs[b];
    const int gidx = group_inputs[b];

    // ---- small hot loads (independent; overlap DMA) ----
    const float itx = item_table[(size_t)iidx * DD + m];        // k = m
    const float ity = item_table[(size_t)iidx * DD + 32 + m];   // k = 32+m
    const float4* wa = (const float4*)(att_w1 + (64 + m) * 16);
    const float4* wb = (const float4*)(att_w1 + (96 + m) * 16);

    // ---- DMA 64 member rows -> LDS, 4 rows/instr coalesced (8 line-reqs vs 64) ----
#pragma unroll
    for (int i = 0; i < 16; ++i) {
        const int row   = 4 * i + (wl >> 4);             // 0..63
        const int rmidx = __shfl(midx, row);             // lane 'row' holds row's member idx
        const char* gp  = (const char*)(user_table + (size_t)rmidx * DD)
                        + (((wl & 15) ^ (row & 7)) << 4);   // source-swizzled 16B chunk
        __builtin_amdgcn_global_load_lds(
            (const __attribute__((address_space(1))) void*)gp,
            (__attribute__((address_space(3))) void*)&tile[256 * i],
            16, 0, 0);
    }

    // ---- item half of layer 1 during DMA flight (k = m, 32+m per lane) ----
    float h[16];
#pragma unroll
    for (int q4 = 0; q4 < 4; ++q4) {
        const float4 a  = wa[q4];
        const float4 bq = wb[q4];
        h[4 * q4 + 0] = fmaf(ity, bq.x, itx * a.x);
        h[4 * q4 + 1] = fmaf(ity, bq.y, itx * a.y);
        h[4 * q4 + 2] = fmaf(ity, bq.z, itx * a.z);
        h[4 * q4 + 3] = fmaf(ity, bq.w, itx * a.w);
    }
#pragma unroll
    for (int i = 0; i < 16; ++i)
        h[i] = half_sum(h[i]) + att_b1[i];

    // ---- wait for DMA (compiler can't see the LDS dependency) ----
    asm volatile("s_waitcnt vmcnt(0)" ::: "memory");
    __builtin_amdgcn_sched_barrier(0);

    // ---- member half: lane reads its own row from LDS, SGPR-uniform weights ----
#pragma unroll
    for (int q = 0; q < 4; ++q) {
#pragma unroll
        for (int kk = 0; kk < 4; ++kk) {
            const int c  = 4 * q + kk;                    // logical chunk: k = 4c..4c+3
            const int sw = c ^ (wl & 7);                  // swizzled chunk
            const float4 v = *(const float4*)&tile[wl * 64 + sw * 4];
            const float* wr = att_w1 + c * 4 * 16;        // uniform rows -> s_load
#pragma unroll
            for (int oo = 0; oo < 16; ++oo) {
                h[oo] = fmaf(v.x, wr[oo],      h[oo]);
                h[oo] = fmaf(v.y, wr[16 + oo], h[oo]);
                h[oo] = fmaf(v.z, wr[32 + oo], h[oo]);
                h[oo] = fmaf(v.w, wr[48 + oo], h[oo]);
            }
        }
    }

    // ---- layer 2 + score ----
    float sc = att_b2[0];
#pragma unroll
    for (int oo = 0; oo < 16; ++oo)
        sc = fmaf(fmaxf(h[oo], 0.f), att_w2[oo], sc);

    // ---- softmax over 32 members ----
    const float smax = half_max(sc);
    const float e    = expf(sc - smax);
    const float ssum = half_sum(e);
    const float w    = e / ssum;
    out[(size_t)BB * 193 + (size_t)b * GG + m] = w;            // at_wt

    const float wmax = 1.0f / ssum;                            // = max softmax weight
    const int   idx  = half_min_i((sc == smax) ? m : 1000);    // first-max index

    // ---- routing classifier ----
    const float cs0 = fmaf(wmax, cls_w[0], cls_b[0]);
    const float cs1 = fmaf(wmax, cls_w[1], cls_b[1]) + 0.5f;
    const int pred  = (cs1 > cs0) ? 1 : 0;

    // ---- g_att: leader (whp) or weighted sum — both served from the LDS tile ----
    float gA, gB;
    if (pred) {
        const int lrow = 32 * hw + idx;
        const int eB   = m + 32;
        gA = tile[lrow * 64 + (((m  >> 2) ^ (lrow & 7)) << 2) + (m  & 3)];
        gB = tile[lrow * 64 + (((eB >> 2) ^ (lrow & 7)) << 2) + (eB & 3)];
    } else {
        float accA = 0.f, accB = 0.f;
        for (int g = 0; g < GG; ++g) {
            const float wg  = __shfl(w, 32 * hw + g);
            const int   row = 32 * hw + g;
            const int   eB  = m + 32;
            accA = fmaf(wg, tile[row * 64 + (((m  >> 2) ^ (row & 7)) << 2) + (m  & 3)], accA);
            accB = fmaf(wg, tile[row * 64 + (((eB >> 2) ^ (row & 7)) << 2) + (eB & 3)], accB);
        }
        gA = accA; gB = accB;
    }

    // ---- group-pure + elementwise + new_embeds outputs ----
    const float gpA = group_table[(size_t)gidx * DD + m]      + group_embedds[(size_t)gidx * DD + m];
    const float gpB = group_table[(size_t)gidx * DD + m + 32] + group_embedds[(size_t)gidx * DD + m + 32];
    const float itA = item_table[(size_t)iidx * DD + m];
    const float itB = item_table[(size_t)iidx * DD + m + 32];
    const float gvA = gA + gpA, gvB = gB + gpB;
    const float elA = gvA * itA, elB = gvB * itB;

    const size_t nb = (size_t)b * 192;
    out[nb + m]        = elA;  out[nb + 32 + m]  = elB;   // elem
    out[nb + 64 + m]   = gvA;  out[nb + 96 + m]  = gvB;   // g
    out[nb + 128 + m]  = itA;  out[nb + 160 + m] = itB;   // item

    // ---- predict MLP: 192 -> 8 (relu) -> 1 (sigmoid) ----
    float p8[8];
#pragma unroll
    for (int j = 0; j < 8; ++j) p8[j] = 0.f;
    {
        const float vals[6] = { elA, elB, gvA, gvB, itA, itB };
        const int   cols[6] = { m, m + 32, 64 + m, 96 + m, 128 + m, 160 + m };
#pragma unroll
        for (int t = 0; t < 6; ++t) {
            const float4* wr = (const float4*)(pred_w1 + cols[t] * 8);
            const float4 w0 = wr[0], w1v = wr[1];
            p8[0] = fmaf(vals[t], w0.x, p8[0]);
            p8[1] = fmaf(vals[t], w0.y, p8[1]);
            p8[2] = fmaf(vals[t], w0.z, p8[2]);
            p8[3] = fmaf(vals[t], w0.w, p8[3]);
            p8[4] = fmaf(vals[t], w1v.x, p8[4]);
            p8[5] = fmaf(vals[t], w1v.y, p8[5]);
            p8[6] = fmaf(vals[t], w1v.z, p8[6]);
            p8[7] = fmaf(vals[t], w1v.w, p8[7]);
        }
    }
#pragma unroll
    for (int j = 0; j < 8; ++j)
        p8[j] = half_sum(p8[j]) + pred_b1[j];

    float t2 = pred_b2[0];
#pragma unroll
    for (int j = 0; j < 8; ++j)
        t2 = fmaf(fmaxf(p8[j], 0.f), pred_w2[j], t2);
    const float yv = 1.f / (1.f + expf(-t2));

    if (m == 0) {
        out[(size_t)BB * 192 + b] = yv;            // y
        out[(size_t)BB * 225 + b] = (float)pred;   // pred_cls
    }
}

extern "C" void kernel_launch(void* const* d_in, const int* in_sizes, int n_in,
                              void* d_out, int out_size, void* d_ws, size_t ws_size,
                              hipStream_t stream) {
    const int*   group_inputs  = (const int*)d_in[0];
    const int*   item_inputs   = (const int*)d_in[1];
    const int*   members       = (const int*)d_in[2];
    const float* user_table    = (const float*)d_in[3];
    const float* item_table    = (const float*)d_in[4];
    const float* group_table   = (const float*)d_in[5];
    const float* group_embedds = (const float*)d_in[6];
    const float* att_w1  = (const float*)d_in[7];
    const float* att_b1  = (const float*)d_in[8];
    const float* att_w2  = (const float*)d_in[9];
    const float* att_b2  = (const float*)d_in[10];
    const float* cls_w   = (const float*)d_in[11];
    const float* cls_b   = (const float*)d_in[12];
    const float* pred_w1 = (const float*)d_in[13];
    const float* pred_b1 = (const float*)d_in[14];
    const float* pred_w2 = (const float*)d_in[15];
    const float* pred_b2 = (const float*)d_in[16];
    float* out = (float*)d_out;

    hipLaunchKernelGGL(hhgr_kernel, dim3(BB / 2), dim3(64), 0, stream,
                       group_inputs, item_inputs, members, user_table, item_table,
                       group_table, group_embedds, att_w1, att_b1, att_w2, att_b2,
                       cls_w, cls_b, pred_w1, pred_b1, pred_w2, pred_b2, out);
}